// Round 2
// baseline (474.819 us; speedup 1.0000x reference)
//
#include <hip/hip_runtime.h>

#define D_NODE    128
#define N_BASIS   9
#define AH_STRIDE 16                   // _Float16 per atoms row (32 B, cache-line aligned)
#define D_EDGE    128

#define BLOCK_C 512
#define TPT     2                      // triples per thread
#define CHUNK   (BLOCK_C * TPT)        // 1024 triples per block
#define SEG_CAP 384                    // LDS segment-range capacity

typedef _Float16 half8 __attribute__((ext_vector_type(8)));

#define AS1(p) ((const __attribute__((address_space(1))) void*)(p))
#define AS3(p) ((__attribute__((address_space(3))) void*)(p))

__device__ __forceinline__ float fast_sigmoid(float x) {
    return __builtin_amdgcn_rcpf(1.0f + __expf(-x));
}

// Kernel A: atoms[a][b] = sigmoid(node_feat[a,:] @ W_atom[:,b] + b_atom[b]),
// stored fp16 with row stride AH_STRIDE halves (32 B -> rows never straddle a line).
__global__ __launch_bounds__(256) void atoms_kernel(
    const float* __restrict__ node_feat,
    const float* __restrict__ W_atom,
    const float* __restrict__ b_atom,
    _Float16* __restrict__ atoms, int n_atoms)
{
    __shared__ float sW[D_NODE * N_BASIS];
    for (int t = threadIdx.x; t < D_NODE * N_BASIS; t += 256)
        sW[t] = W_atom[t];
    __syncthreads();
    int idx = blockIdx.x * 256 + threadIdx.x;
    int total = n_atoms * N_BASIS;
    if (idx >= total) return;
    int a = idx / N_BASIS;
    int b = idx - a * N_BASIS;
    const float* row = node_feat + a * D_NODE;
    float acc = b_atom[b];
#pragma unroll 8
    for (int i = 0; i < D_NODE; ++i)
        acc += row[i] * sW[i * N_BASIS + b];
    atoms[a * AH_STRIDE + b] = (_Float16)fast_sigmoid(acc);
}

#define FLUSH_RUN()                                                          \
    do {                                                                     \
        if (use_lds) {                                                       \
            float* dst_ = lacc + (cur - seg_first) * N_BASIS;                \
            _Pragma("unroll")                                                \
            for (int k_ = 0; k_ < N_BASIS; ++k_)                             \
                atomicAdd(&dst_[k_], sum[k_]);                               \
        } else {                                                             \
            float* dst_ = new_bonds + (size_t)cur * N_BASIS;                 \
            _Pragma("unroll")                                                \
            for (int k_ = 0; k_ < N_BASIS; ++k_)                             \
                unsafeAtomicAdd(&dst_[k_], sum[k_]);                         \
        }                                                                    \
    } while (0)

// Kernel C: streaming segmented reduction over sorted triples.
// three_basis staged to LDS with coalesced direct-to-LDS DMA (the per-lane
// 144B-stride float4 loads of the old version were 64-line gathers and the
// dominant TA-request cost). atoms gathered as fp16 (line-aligned, 1-2 reqs).
__global__ __launch_bounds__(BLOCK_C) void triple_kernel(
    const float* __restrict__ three_basis,
    const _Float16* __restrict__ atoms,
    const int*   __restrict__ graph_dst,
    const int*   __restrict__ lg_dst,
    const int*   __restrict__ seg,
    float* __restrict__ new_bonds,
    int n_triples)
{
    __shared__ float stb[CHUNK * N_BASIS];     // 36864 B staged three_basis
    __shared__ float lacc[SEG_CAP * N_BASIS];  // 13824 B
    __shared__ int sh_first, sh_last;

    const int tid = threadIdx.x;
    const int chunk_start = blockIdx.x * CHUNK;
    const int t0 = chunk_start + tid * TPT;

    // ---- stage this chunk of three_basis into LDS, coalesced, no VGPR round-trip.
    // LDS dest is wave-uniform (base); HW adds lane*16. Global src is per-lane.
    // nfull is always a multiple of 64 here (36B rows, chunk multiple of 16 triples),
    // so the i<nfull predicate is wave-uniform.
    {
        int avail = (n_triples - chunk_start) * (N_BASIS * 4);
        int full_bytes = avail > CHUNK * N_BASIS * 4 ? CHUNK * N_BASIS * 4 : avail;
        int nfull = full_bytes >> 4;           // whole 16-B chunks
        const char* gsrc = (const char*)three_basis + (size_t)chunk_start * (N_BASIS * 4);
        const int lane = tid & 63;
        for (int base = (tid >> 6) * 64; base < nfull; base += BLOCK_C) {
            int i = base + lane;
            if (i < nfull) {
                __builtin_amdgcn_global_load_lds(
                    AS1(gsrc + (size_t)i * 16),
                    AS3((char*)stb + (size_t)base * 16),
                    16, 0, 0);
            }
        }
        int rem = full_bytes - (nfull << 4);   // 0/4/8/12 B (generic-shape safety)
        if ((tid << 2) < rem)
            ((float*)stb)[nfull * 4 + tid] = ((const float*)gsrc)[nfull * 4 + tid];
    }

    if (tid == 0) sh_first = seg[chunk_start];
    if (tid == BLOCK_C - 1) {
        int last = chunk_start + CHUNK;
        if (last > n_triples) last = n_triples;
        sh_last = seg[last - 1];
    }
    for (int i = tid; i < SEG_CAP * N_BASIS; i += BLOCK_C)
        lacc[i] = 0.0f;

    // ---- per-thread gathers issued BEFORE the barrier: latency hides under DMA wait
    const bool fast = (t0 + TPT <= n_triples);
    int sg0 = 0, sg1 = 0;
    half8 h0, h1;
    _Float16 e0h = (_Float16)0.f, e1h = (_Float16)0.f;
    if (fast) {
        int2 sg2 = *(const int2*)(seg + t0);
        int2 ld2 = *(const int2*)(lg_dst + t0);
        sg0 = sg2.x; sg1 = sg2.y;
        int ai0 = graph_dst[ld2.x];
        int ai1 = graph_dst[ld2.y];
        const _Float16* ap0 = atoms + (size_t)ai0 * AH_STRIDE;
        const _Float16* ap1 = atoms + (size_t)ai1 * AH_STRIDE;
        h0 = *(const half8*)ap0;               // 16 B, aligned (stride 32 B)
        h1 = *(const half8*)ap1;
        e0h = ap0[8];
        e1h = ap1[8];
    }

    __syncthreads();   // compiler drains vmcnt (incl. global_load_lds) before s_barrier

    const int seg_first = sh_first;
    const int range = sh_last - seg_first + 1;
    const bool use_lds = (range <= SEG_CAP);

    if (fast) {
        const float* tbl = stb + tid * (TPT * N_BASIS);   // 18-float stride: 2-way banks (free)
        float sum[N_BASIS];
        int cur = sg0;
#pragma unroll
        for (int k = 0; k < 8; ++k) sum[k] = tbl[k] * (float)h0[k];
        sum[8] = tbl[8] * (float)e0h;
        if (sg1 != cur) {
            FLUSH_RUN();
            cur = sg1;
#pragma unroll
            for (int k = 0; k < 8; ++k) sum[k] = tbl[N_BASIS + k] * (float)h1[k];
            sum[8] = tbl[N_BASIS + 8] * (float)e1h;
        } else {
#pragma unroll
            for (int k = 0; k < 8; ++k) sum[k] += tbl[N_BASIS + k] * (float)h1[k];
            sum[8] += tbl[N_BASIS + 8] * (float)e1h;
        }
        FLUSH_RUN();
    } else if (t0 < n_triples) {
        // tail path (unused when n_triples % TPT == 0): reads global directly
        int tend = t0 + TPT; if (tend > n_triples) tend = n_triples;
        for (int t = t0; t < tend; ++t) {
            int cur = seg[t];
            int atom = graph_dst[lg_dst[t]];
            const float* tbr = three_basis + (size_t)t * N_BASIS;
            const _Float16* ar = atoms + (size_t)atom * AH_STRIDE;
            float sum[N_BASIS];
#pragma unroll
            for (int k = 0; k < N_BASIS; ++k) sum[k] = tbr[k] * (float)ar[k];
            FLUSH_RUN();
        }
    }

    __syncthreads();

    if (use_lds) {
        int total = range * N_BASIS;
        for (int idx = tid; idx < total; idx += BLOCK_C) {
            int r = idx / N_BASIS;
            int k = idx - r * N_BASIS;
            float v = lacc[idx];
            int s = seg_first + r;
            if (r == 0 || r == range - 1) {
                if (v != 0.0f)
                    unsafeAtomicAdd(&new_bonds[(size_t)s * N_BASIS + k], v);
            } else {
                new_bonds[(size_t)s * N_BASIS + k] = v;   // fully owned
            }
        }
    }
}

// Kernel D: per-edge gated MLP 9 -> 128 + residual. 32 threads x 4 edges per
// group (W fragments reused across 4 edges in registers -> 4x fewer W fetches).
__global__ __launch_bounds__(256) void mlp_kernel(
    const float* __restrict__ edge_feat,
    const float* __restrict__ new_bonds,
    const float* __restrict__ W_gate, const float* __restrict__ b_gate,
    const float* __restrict__ W_sig,  const float* __restrict__ b_sig,
    float* __restrict__ out, int n_edges)
{
    const int tid  = threadIdx.x;
    const int grp  = tid >> 5;               // 8 groups/block
    const int c    = (tid & 31) * 4;         // channel base
    const int e0   = (blockIdx.x * 8 + grp) * 4;
    if (e0 >= n_edges) return;
    const int nvalid = (n_edges - e0) < 4 ? (n_edges - e0) : 4;

    float nb[4][N_BASIS];
#pragma unroll
    for (int j = 0; j < 4; ++j) {
        const float* nbr = new_bonds + (size_t)(e0 + (j < nvalid ? j : 0)) * N_BASIS;
#pragma unroll
        for (int k = 0; k < N_BASIS; ++k) nb[j][k] = nbr[k];   // broadcast across group
    }

    float4 bg = *(const float4*)(b_gate + c);
    float4 bs = *(const float4*)(b_sig + c);
    float4 g[4], s[4];
#pragma unroll
    for (int j = 0; j < 4; ++j) { g[j] = bg; s[j] = bs; }

#pragma unroll
    for (int k = 0; k < N_BASIS; ++k) {
        float4 wg = *(const float4*)(W_gate + k * D_EDGE + c);
        float4 ws = *(const float4*)(W_sig  + k * D_EDGE + c);
#pragma unroll
        for (int j = 0; j < 4; ++j) {
            g[j].x += nb[j][k] * wg.x; g[j].y += nb[j][k] * wg.y;
            g[j].z += nb[j][k] * wg.z; g[j].w += nb[j][k] * wg.w;
            s[j].x += nb[j][k] * ws.x; s[j].y += nb[j][k] * ws.y;
            s[j].z += nb[j][k] * ws.z; s[j].w += nb[j][k] * ws.w;
        }
    }

#pragma unroll
    for (int j = 0; j < 4; ++j) {
        if (j < nvalid) {
            int e = e0 + j;
            float4 ef = *(const float4*)(edge_feat + (size_t)e * D_EDGE + c);
            float4 o;
            o.x = ef.x + g[j].x * fast_sigmoid(g[j].x) * fast_sigmoid(s[j].x);
            o.y = ef.y + g[j].y * fast_sigmoid(g[j].y) * fast_sigmoid(s[j].y);
            o.z = ef.z + g[j].z * fast_sigmoid(g[j].z) * fast_sigmoid(s[j].z);
            o.w = ef.w + g[j].w * fast_sigmoid(g[j].w) * fast_sigmoid(s[j].w);
            *(float4*)(out + (size_t)e * D_EDGE + c) = o;
        }
    }
}

extern "C" void kernel_launch(void* const* d_in, const int* in_sizes, int n_in,
                              void* d_out, int out_size, void* d_ws, size_t ws_size,
                              hipStream_t stream) {
    const float* node_feat   = (const float*)d_in[0];
    const float* edge_feat   = (const float*)d_in[1];
    const float* three_basis = (const float*)d_in[2];
    // d_in[3] three_cutoff: dead code in reference
    const float* W_atom      = (const float*)d_in[4];
    const float* b_atom      = (const float*)d_in[5];
    const float* W_gate      = (const float*)d_in[6];
    const float* b_gate      = (const float*)d_in[7];
    const float* W_sig       = (const float*)d_in[8];
    const float* b_sig       = (const float*)d_in[9];
    const int*   graph_dst   = (const int*)d_in[10];
    // d_in[11] lg_src: dead code in reference
    const int*   lg_dst      = (const int*)d_in[12];
    const int*   seg         = (const int*)d_in[13];

    int n_atoms   = in_sizes[0] / D_NODE;
    int n_edges   = in_sizes[1] / D_EDGE;
    int n_triples = in_sizes[2] / N_BASIS;

    // ws layout: atoms fp16 [n_atoms*16 halves, padded] | new_bonds [n_edges*9 f32]
    _Float16* atoms = (_Float16*)d_ws;
    size_t atoms_bytes = ((size_t)n_atoms * AH_STRIDE * sizeof(_Float16) + 255) & ~(size_t)255;
    float* new_bonds = (float*)((char*)d_ws + atoms_bytes);
    size_t nb_bytes = (size_t)n_edges * N_BASIS * sizeof(float);

    hipMemsetAsync(new_bonds, 0, nb_bytes, stream);

    atoms_kernel<<<(n_atoms * N_BASIS + 255) / 256, 256, 0, stream>>>(
        node_feat, W_atom, b_atom, atoms, n_atoms);

    triple_kernel<<<(n_triples + CHUNK - 1) / CHUNK, BLOCK_C, 0, stream>>>(
        three_basis, atoms, graph_dst, lg_dst, seg, new_bonds, n_triples);

    mlp_kernel<<<(n_edges + 31) / 32, 256, 0, stream>>>(
        edge_feat, new_bonds, W_gate, b_gate, W_sig, b_sig, (float*)d_out, n_edges);
}

// Round 3
// 420.451 us; speedup vs baseline: 1.1293x; 1.1293x over previous
//
#include <hip/hip_runtime.h>

#define D_NODE    128
#define N_BASIS   9
#define AH_STRIDE 16                   // _Float16 row stride (32 B, line-aligned)
#define D_EDGE    128

#define BLOCK_C 256
#define TPT     4                      // triples per thread
#define CHUNK   (BLOCK_C * TPT)        // 1024 triples per block
#define SEG_CAP 512                    // LDS segment-range capacity

typedef _Float16 half8 __attribute__((ext_vector_type(8)));

__device__ __forceinline__ float fast_sigmoid(float x) {
    return __builtin_amdgcn_rcpf(1.0f + __expf(-x));
}

// Kernel A: atoms[a][b] = sigmoid(node_feat[a,:] @ W_atom[:,b] + b_atom[b]),
// stored fp16 with 32-B row stride (rows never straddle a cache line).
__global__ __launch_bounds__(256) void atoms_kernel(
    const float* __restrict__ node_feat,
    const float* __restrict__ W_atom,
    const float* __restrict__ b_atom,
    _Float16* __restrict__ atoms, int n_atoms)
{
    __shared__ float sW[D_NODE * N_BASIS];
    for (int t = threadIdx.x; t < D_NODE * N_BASIS; t += 256)
        sW[t] = W_atom[t];
    __syncthreads();
    int idx = blockIdx.x * 256 + threadIdx.x;
    int total = n_atoms * N_BASIS;
    if (idx >= total) return;
    int a = idx / N_BASIS;
    int b = idx - a * N_BASIS;
    const float* row = node_feat + a * D_NODE;
    float acc = b_atom[b];
#pragma unroll 8
    for (int i = 0; i < D_NODE; ++i)
        acc += row[i] * sW[i * N_BASIS + b];
    atoms[a * AH_STRIDE + b] = (_Float16)fast_sigmoid(acc);
}

// Kernel B: edge_atoms[e] = atoms[graph_dst[e]]  (collapses one gather hop
// out of the 4M-triple inner loop; 200K edges -> ~5 us).
__global__ __launch_bounds__(256) void edge_atoms_kernel(
    const _Float16* __restrict__ atoms,
    const int* __restrict__ graph_dst,
    _Float16* __restrict__ ea, int n_edges)
{
    int e = blockIdx.x * 256 + threadIdx.x;
    if (e >= n_edges) return;
    int a = graph_dst[e];
    const _Float16* ap = atoms + (size_t)a * AH_STRIDE;
    half8 h = *(const half8*)ap;
    _Float16 h8 = ap[8];
    _Float16* dp = ea + (size_t)e * AH_STRIDE;
    *(half8*)dp = h;
    dp[8] = h8;
}

#define FLUSH_RUN()                                                          \
    do {                                                                     \
        if (use_lds) {                                                       \
            float* dst_ = lacc + (cur - seg_first) * N_BASIS;                \
            _Pragma("unroll")                                                \
            for (int k_ = 0; k_ < N_BASIS; ++k_)                             \
                atomicAdd(&dst_[k_], sum[k_]);                               \
        } else {                                                             \
            float* dst_ = new_bonds + (size_t)cur * N_BASIS;                 \
            _Pragma("unroll")                                                \
            for (int k_ = 0; k_ < N_BASIS; ++k_)                             \
                unsafeAtomicAdd(&dst_[k_], sum[k_]);                         \
        }                                                                    \
    } while (0)

// Kernel C: streaming segmented reduction over sorted triples.
// R0's concurrency structure (no staging barrier, 18.9 KB LDS, 8 blocks/CU)
// + 2-hop gather (lg_dst -> edge_atoms) when EA, else 3-hop fallback.
template<bool EA>
__global__ __launch_bounds__(BLOCK_C) void triple_kernel(
    const float* __restrict__ three_basis,
    const _Float16* __restrict__ atab,     // EA ? edge_atoms : atoms
    const int*   __restrict__ graph_dst,   // used only when !EA
    const int*   __restrict__ lg_dst,
    const int*   __restrict__ seg,
    float* __restrict__ new_bonds,
    int n_triples)
{
    __shared__ float lacc[SEG_CAP * N_BASIS];   // 18432 B
    __shared__ int sh_first, sh_last;

    const int tid = threadIdx.x;
    const int chunk_start = blockIdx.x * CHUNK;
    const int t0 = chunk_start + tid * TPT;

    if (tid == 0) sh_first = seg[chunk_start];
    if (tid == BLOCK_C - 1) {
        int last = chunk_start + CHUNK;
        if (last > n_triples) last = n_triples;
        sh_last = seg[last - 1];
    }
    for (int i = tid; i < SEG_CAP * N_BASIS; i += BLOCK_C)
        lacc[i] = 0.0f;
    __syncthreads();

    const int seg_first = sh_first;
    const int range = sh_last - seg_first + 1;
    const bool use_lds = (range <= SEG_CAP);

    if (t0 + TPT <= n_triples) {
        // ---- fast path: everything compile-time indexed ----
        float tb[TPT * N_BASIS];
        const float4* tb4 = (const float4*)(three_basis + (size_t)t0 * N_BASIS);
#pragma unroll
        for (int q = 0; q < 9; ++q)
            *(float4*)&tb[q * 4] = tb4[q];      // constant index after unroll

        const int4 sg4 = *(const int4*)(seg + t0);
        const int4 ld4 = *(const int4*)(lg_dst + t0);
        int sgs[TPT] = { sg4.x, sg4.y, sg4.z, sg4.w };

        int ridx[TPT];
        if (EA) {
            ridx[0] = ld4.x; ridx[1] = ld4.y; ridx[2] = ld4.z; ridx[3] = ld4.w;
        } else {
            ridx[0] = graph_dst[ld4.x];
            ridx[1] = graph_dst[ld4.y];
            ridx[2] = graph_dst[ld4.z];
            ridx[3] = graph_dst[ld4.w];
        }
        // issue all 4 row gathers up front (independent, 1 line each)
        half8 hh[TPT];
        _Float16 h8[TPT];
#pragma unroll
        for (int i = 0; i < TPT; ++i) {
            const _Float16* ap = atab + (size_t)ridx[i] * AH_STRIDE;
            hh[i] = *(const half8*)ap;          // 16 B aligned (32-B stride)
            h8[i] = ap[8];
        }

        float sum[N_BASIS];
        int cur = sgs[0];
#pragma unroll
        for (int k = 0; k < N_BASIS; ++k) sum[k] = 0.0f;

#pragma unroll
        for (int i = 0; i < TPT; ++i) {
            if (sgs[i] != cur) {
                FLUSH_RUN();
                cur = sgs[i];
#pragma unroll
                for (int k = 0; k < N_BASIS; ++k) sum[k] = 0.0f;
            }
#pragma unroll
            for (int k = 0; k < 8; ++k)
                sum[k] += tb[i * N_BASIS + k] * (float)hh[i][k];
            sum[8] += tb[i * N_BASIS + 8] * (float)h8[i];
        }
        FLUSH_RUN();
    } else if (t0 < n_triples) {
        // ---- array-free tail path (unused when n_triples % 4 == 0) ----
        for (int t = t0; t < n_triples; ++t) {
            int cur = seg[t];
            int r = EA ? lg_dst[t] : graph_dst[lg_dst[t]];
            const float* tbr = three_basis + (size_t)t * N_BASIS;
            const _Float16* ar = atab + (size_t)r * AH_STRIDE;
            float sum[N_BASIS];
#pragma unroll
            for (int k = 0; k < N_BASIS; ++k) sum[k] = tbr[k] * (float)ar[k];
            FLUSH_RUN();
        }
    }

    __syncthreads();

    if (use_lds) {
        int total = range * N_BASIS;
        for (int idx = tid; idx < total; idx += BLOCK_C) {
            int r = idx / N_BASIS;
            int k = idx - r * N_BASIS;
            float v = lacc[idx];
            int s = seg_first + r;
            if (r == 0 || r == range - 1) {
                if (v != 0.0f)
                    unsafeAtomicAdd(&new_bonds[(size_t)s * N_BASIS + k], v);
            } else {
                new_bonds[(size_t)s * N_BASIS + k] = v;   // fully owned
            }
        }
    }
}

// Kernel D: per-edge gated MLP 9 -> 128 + residual. 32 threads x 4 edges per
// group (W fragments reused across 4 edges in registers -> 4x fewer W fetches).
__global__ __launch_bounds__(256) void mlp_kernel(
    const float* __restrict__ edge_feat,
    const float* __restrict__ new_bonds,
    const float* __restrict__ W_gate, const float* __restrict__ b_gate,
    const float* __restrict__ W_sig,  const float* __restrict__ b_sig,
    float* __restrict__ out, int n_edges)
{
    const int tid  = threadIdx.x;
    const int grp  = tid >> 5;               // 8 groups/block
    const int c    = (tid & 31) * 4;         // channel base
    const int e0   = (blockIdx.x * 8 + grp) * 4;
    if (e0 >= n_edges) return;
    const int nvalid = (n_edges - e0) < 4 ? (n_edges - e0) : 4;

    float nb[4][N_BASIS];
#pragma unroll
    for (int j = 0; j < 4; ++j) {
        const float* nbr = new_bonds + (size_t)(e0 + (j < nvalid ? j : 0)) * N_BASIS;
#pragma unroll
        for (int k = 0; k < N_BASIS; ++k) nb[j][k] = nbr[k];   // broadcast across group
    }

    float4 bg = *(const float4*)(b_gate + c);
    float4 bs = *(const float4*)(b_sig + c);
    float4 g[4], s[4];
#pragma unroll
    for (int j = 0; j < 4; ++j) { g[j] = bg; s[j] = bs; }

#pragma unroll
    for (int k = 0; k < N_BASIS; ++k) {
        float4 wg = *(const float4*)(W_gate + k * D_EDGE + c);
        float4 ws = *(const float4*)(W_sig  + k * D_EDGE + c);
#pragma unroll
        for (int j = 0; j < 4; ++j) {
            g[j].x += nb[j][k] * wg.x; g[j].y += nb[j][k] * wg.y;
            g[j].z += nb[j][k] * wg.z; g[j].w += nb[j][k] * wg.w;
            s[j].x += nb[j][k] * ws.x; s[j].y += nb[j][k] * ws.y;
            s[j].z += nb[j][k] * ws.z; s[j].w += nb[j][k] * ws.w;
        }
    }

#pragma unroll
    for (int j = 0; j < 4; ++j) {
        if (j < nvalid) {
            int e = e0 + j;
            float4 ef = *(const float4*)(edge_feat + (size_t)e * D_EDGE + c);
            float4 o;
            o.x = ef.x + g[j].x * fast_sigmoid(g[j].x) * fast_sigmoid(s[j].x);
            o.y = ef.y + g[j].y * fast_sigmoid(g[j].y) * fast_sigmoid(s[j].y);
            o.z = ef.z + g[j].z * fast_sigmoid(g[j].z) * fast_sigmoid(s[j].z);
            o.w = ef.w + g[j].w * fast_sigmoid(g[j].w) * fast_sigmoid(s[j].w);
            *(float4*)(out + (size_t)e * D_EDGE + c) = o;
        }
    }
}

extern "C" void kernel_launch(void* const* d_in, const int* in_sizes, int n_in,
                              void* d_out, int out_size, void* d_ws, size_t ws_size,
                              hipStream_t stream) {
    const float* node_feat   = (const float*)d_in[0];
    const float* edge_feat   = (const float*)d_in[1];
    const float* three_basis = (const float*)d_in[2];
    // d_in[3] three_cutoff: dead code in reference
    const float* W_atom      = (const float*)d_in[4];
    const float* b_atom      = (const float*)d_in[5];
    const float* W_gate      = (const float*)d_in[6];
    const float* b_gate      = (const float*)d_in[7];
    const float* W_sig       = (const float*)d_in[8];
    const float* b_sig       = (const float*)d_in[9];
    const int*   graph_dst   = (const int*)d_in[10];
    // d_in[11] lg_src: dead code in reference
    const int*   lg_dst      = (const int*)d_in[12];
    const int*   seg         = (const int*)d_in[13];

    int n_atoms   = in_sizes[0] / D_NODE;
    int n_edges   = in_sizes[1] / D_EDGE;
    int n_triples = in_sizes[2] / N_BASIS;

    // ws layout: atoms fp16 | [edge_atoms fp16] | new_bonds f32
    size_t atoms_bytes = ((size_t)n_atoms * AH_STRIDE * sizeof(_Float16) + 255) & ~(size_t)255;
    size_t ea_bytes    = ((size_t)n_edges * AH_STRIDE * sizeof(_Float16) + 255) & ~(size_t)255;
    size_t nb_bytes    = (size_t)n_edges * N_BASIS * sizeof(float);

    bool use_ea = (ws_size >= atoms_bytes + ea_bytes + nb_bytes);

    _Float16* atoms = (_Float16*)d_ws;
    _Float16* ea    = (_Float16*)((char*)d_ws + atoms_bytes);
    float* new_bonds = (float*)((char*)d_ws + atoms_bytes + (use_ea ? ea_bytes : 0));

    hipMemsetAsync(new_bonds, 0, nb_bytes, stream);

    atoms_kernel<<<(n_atoms * N_BASIS + 255) / 256, 256, 0, stream>>>(
        node_feat, W_atom, b_atom, atoms, n_atoms);

    if (use_ea) {
        edge_atoms_kernel<<<(n_edges + 255) / 256, 256, 0, stream>>>(
            atoms, graph_dst, ea, n_edges);
        triple_kernel<true><<<(n_triples + CHUNK - 1) / CHUNK, BLOCK_C, 0, stream>>>(
            three_basis, ea, graph_dst, lg_dst, seg, new_bonds, n_triples);
    } else {
        triple_kernel<false><<<(n_triples + CHUNK - 1) / CHUNK, BLOCK_C, 0, stream>>>(
            three_basis, atoms, graph_dst, lg_dst, seg, new_bonds, n_triples);
    }

    mlp_kernel<<<(n_edges + 31) / 32, 256, 0, stream>>>(
        edge_feat, new_bonds, W_gate, b_gate, W_sig, b_sig, (float*)d_out, n_edges);
}